// Round 7
// baseline (256.884 us; speedup 1.0000x reference)
//
#include <hip/hip_runtime.h>
#include <math.h>

// Problem constants
#define BB 8
#define LL 1024
#define SS 1024
#define CC 128
#define NN 8
#define PP 256

static constexpr float EPS       = 1e-6f;
static constexpr float ONE_M_EPS = 1.0f - 1e-6f;
static constexpr float INV_T     = 1.0f / 0.07f;
static constexpr float NLL_MAX   = 13.815511f;    // -log(1e-6)
static constexpr float NLL_MIN   = 1.0000005e-6f; // -log(1-1e-6)

// Workspace layout (float offsets)
static constexpr size_t DOTSZ      = (size_t)BB * LL * SS;   // 8388608
static constexpr size_t OFF_LSER   = DOTSZ;                  // B*L
static constexpr size_t OFF_LSEC   = DOTSZ + 16384;          // B*S
static constexpr size_t OFF_SHARP2 = DOTSZ + 32768;          // B*L
static constexpr size_t OFF_RP     = DOTSZ + 40960;          // row partials: 8*16*1024*4 = 524288
static constexpr size_t OFF_CP     = OFF_RP + 524288;        // col partials: 524288
static constexpr size_t OFF_ACC    = OFF_CP + 524288;        // B*6 loss accumulators
static constexpr size_t OFF_DONE   = OFF_ACC + 48;           // done counter (unsigned)
static constexpr size_t OFF_CLP    = OFF_ACC + 64;           // 32 contrast blocks x {pos,neg}

// Output layout (floats): sharp1[8192], cl_pos_save[1024], total, geo_pos, geo_neg, loss_sharp, loss_cl
static constexpr int OUT_CLSAVE = 8192;
static constexpr int OUT_SCAL   = 9216;

typedef __bf16 bf16x8 __attribute__((ext_vector_type(8)));
typedef float  floatx4 __attribute__((ext_vector_type(4)));

__device__ __forceinline__ bf16x8 mkfrag(unsigned a, unsigned b, unsigned c, unsigned d) {
    uint4 t = make_uint4(a, b, c, d);
    return __builtin_bit_cast(bf16x8, t);
}

// Split 4 fp32 into packed bf16 hi pairs (RNE) + lo pairs (exact residual, truncated).
__device__ __forceinline__ void split_f4(float4 x,
                                         unsigned& hp0, unsigned& hp1,
                                         unsigned& lp0, unsigned& lp1) {
    unsigned u0 = __builtin_bit_cast(unsigned, x.x);
    unsigned u1 = __builtin_bit_cast(unsigned, x.y);
    unsigned u2 = __builtin_bit_cast(unsigned, x.z);
    unsigned u3 = __builtin_bit_cast(unsigned, x.w);
    unsigned r0 = u0 + 0x7FFFu + ((u0 >> 16) & 1u);
    unsigned r1 = u1 + 0x7FFFu + ((u1 >> 16) & 1u);
    unsigned r2 = u2 + 0x7FFFu + ((u2 >> 16) & 1u);
    unsigned r3 = u3 + 0x7FFFu + ((u3 >> 16) & 1u);
    float s0 = x.x - __builtin_bit_cast(float, r0 & 0xFFFF0000u);
    float s1 = x.y - __builtin_bit_cast(float, r1 & 0xFFFF0000u);
    float s2 = x.z - __builtin_bit_cast(float, r2 & 0xFFFF0000u);
    float s3 = x.w - __builtin_bit_cast(float, r3 & 0xFFFF0000u);
    hp0 = __builtin_amdgcn_perm(r1, r0, 0x07060302u);
    hp1 = __builtin_amdgcn_perm(r3, r2, 0x07060302u);
    lp0 = __builtin_amdgcn_perm(__builtin_bit_cast(unsigned, s1),
                                __builtin_bit_cast(unsigned, s0), 0x07060302u);
    lp1 = __builtin_amdgcn_perm(__builtin_bit_cast(unsigned, s3),
                                __builtin_bit_cast(unsigned, s2), 0x07060302u);
}

// ============ Kernel 1: gemm+stats (512 blocks) | contrast (32) | misc (1) ============
__global__ __launch_bounds__(256) void k1_gemm(const float* __restrict__ A,
                                               const float* __restrict__ Bm,
                                               const float* __restrict__ q_cl,
                                               const float* __restrict__ cl_pos,
                                               const int* __restrict__ idx,
                                               float* __restrict__ dot,
                                               float* __restrict__ ws,
                                               float* __restrict__ out) {
    __shared__ float qn[8][128];
    __shared__ float sbc[2][4];
    int tid  = threadIdx.x;
    int lane = tid & 63;
    int w    = tid >> 6;

    if (blockIdx.x < 512) {
        // ---- LDS-free split-bf16 MFMA gemm, one wave per 64x64 tile (R5-verified) ----
        int t    = blockIdx.x * 4 + w;      // 0..2047
        int b    = t >> 8;
        int rem  = t & 255;
        int lt   = rem >> 4, st = rem & 15;
        int l0   = lt * 64, s0 = st * 64;
        int fl   = lane & 15;
        int quad = lane >> 4;

        const float* Ab = A  + ((size_t)b * LL + l0) * CC;
        const float* Bb = Bm + ((size_t)b * SS + s0) * CC;

        floatx4 acc[4][4];
#pragma unroll
        for (int i = 0; i < 4; i++)
#pragma unroll
            for (int j = 0; j < 4; j++) acc[i][j] = (floatx4){0.f, 0.f, 0.f, 0.f};

        for (int c0 = 0; c0 < 128; c0 += 32) {
            float4 ax[4][2], bx[4][2];
#pragma unroll
            for (int mt = 0; mt < 4; mt++) {
                const float* p = Ab + (size_t)(mt * 16 + fl) * CC + c0 + quad * 8;
                ax[mt][0] = *(const float4*)p;
                ax[mt][1] = *(const float4*)(p + 4);
            }
#pragma unroll
            for (int nt = 0; nt < 4; nt++) {
                const float* p = Bb + (size_t)(nt * 16 + fl) * CC + c0 + quad * 8;
                bx[nt][0] = *(const float4*)p;
                bx[nt][1] = *(const float4*)(p + 4);
            }
            bf16x8 ah[4], al[4];
#pragma unroll
            for (int mt = 0; mt < 4; mt++) {
                unsigned h0, h1, h2, h3, q0, q1, q2, q3;
                split_f4(ax[mt][0], h0, h1, q0, q1);
                split_f4(ax[mt][1], h2, h3, q2, q3);
                ah[mt] = mkfrag(h0, h1, h2, h3);
                al[mt] = mkfrag(q0, q1, q2, q3);
            }
#pragma unroll
            for (int nt = 0; nt < 4; nt++) {
                unsigned h0, h1, h2, h3, q0, q1, q2, q3;
                split_f4(bx[nt][0], h0, h1, q0, q1);
                split_f4(bx[nt][1], h2, h3, q2, q3);
                bf16x8 bh = mkfrag(h0, h1, h2, h3);
                bf16x8 bl = mkfrag(q0, q1, q2, q3);
#pragma unroll
                for (int mt = 0; mt < 4; mt++) {
                    acc[mt][nt] = __builtin_amdgcn_mfma_f32_16x16x32_bf16(ah[mt], bh, acc[mt][nt], 0, 0, 0);
                    acc[mt][nt] = __builtin_amdgcn_mfma_f32_16x16x32_bf16(ah[mt], bl, acc[mt][nt], 0, 0, 0);
                    acc[mt][nt] = __builtin_amdgcn_mfma_f32_16x16x32_bf16(al[mt], bh, acc[mt][nt], 0, 0, 0);
                }
            }
        }

        // Store dot tile. C/D layout: col=lane&15, row=quad*4+reg
        float* D = dot + ((size_t)b * LL + l0) * SS + s0;
#pragma unroll
        for (int mt = 0; mt < 4; mt++)
#pragma unroll
            for (int nt = 0; nt < 4; nt++) {
                int col = nt * 16 + fl;
#pragma unroll
                for (int r = 0; r < 4; r++) {
                    int row = mt * 16 + quad * 4 + r;
                    D[(size_t)row * SS + col] = acc[mt][nt][r];
                }
            }

        // Fused wave-private tile statistics
        float ces[4], cmx[4], csm[4], csq[4];
#pragma unroll
        for (int nt = 0; nt < 4; nt++) { ces[nt] = 0.f; cmx[nt] = -1e30f; csm[nt] = 0.f; csq[nt] = 0.f; }
#pragma unroll
        for (int mt = 0; mt < 4; mt++) {
#pragma unroll
            for (int r = 0; r < 4; r++) {
                float es = 0.f, mx = -1e30f, sm = 0.f, sq = 0.f;
#pragma unroll
                for (int nt = 0; nt < 4; nt++) {
                    float d  = acc[mt][nt][r];
                    float e  = __expf(d * INV_T);
                    float s2 = fmaf(0.5f, d, 0.5f);
                    es += e; mx = fmaxf(mx, s2); sm += s2; sq += s2 * s2;
                    ces[nt] += e; cmx[nt] = fmaxf(cmx[nt], s2); csm[nt] += s2; csq[nt] += s2 * s2;
                }
                for (int o = 1; o < 16; o <<= 1) {
                    es += __shfl_xor(es, o);
                    mx = fmaxf(mx, __shfl_xor(mx, o));
                    sm += __shfl_xor(sm, o);
                    sq += __shfl_xor(sq, o);
                }
                if (fl == 0) {
                    int row = l0 + mt * 16 + quad * 4 + r;
                    *(float4*)(ws + OFF_RP + (((size_t)(b * 16 + st)) * 1024 + row) * 4) =
                        make_float4(es, mx, sm, sq);
                }
            }
        }
#pragma unroll
        for (int nt = 0; nt < 4; nt++) {
            float es = ces[nt], mx = cmx[nt], sm = csm[nt], sq = csq[nt];
            for (int o = 16; o < 64; o <<= 1) {
                es += __shfl_xor(es, o);
                mx = fmaxf(mx, __shfl_xor(mx, o));
                sm += __shfl_xor(sm, o);
                sq += __shfl_xor(sq, o);
            }
            if (quad == 0) {
                int col = s0 + nt * 16 + fl;
                *(float4*)(ws + OFF_CP + (((size_t)(b * 16 + lt)) * 1024 + col) * 4) =
                    make_float4(es, mx, sm, sq);
            }
        }
    } else if (blockIdx.x < 544) {
        // ---- Contrast: 32 blocks, each 64 j-rows, per-block partial slots ----
        int cb = blockIdx.x - 512;
        // stage normalized q_sel into LDS (wave w handles n=2w,2w+1)
#pragma unroll
        for (int i = 0; i < 2; i++) {
            int n = 2 * w + i;
            int in = idx[n];
            float2 qv = *(const float2*)(q_cl + ((size_t)(n * PP + in)) * CC + 2 * lane);
            float ss = qv.x * qv.x + qv.y * qv.y;
            for (int o = 32; o; o >>= 1) ss += __shfl_xor(ss, o);
            float inv = 1.0f / fmaxf(sqrtf(ss), 1e-12f);
            qn[n][2 * lane]     = qv.x * inv;
            qn[n][2 * lane + 1] = qv.y * inv;
        }
        __syncthreads();
        float pos = 0.f, neg = 0.f;
        for (int jj = 0; jj < 16; jj++) {
            int j = cb * 64 + w * 16 + jj;
            int m, p;
            if (j < NN) { m = j; p = idx[j]; }
            else {
                int t2 = j - NN;
                m = t2 / (PP - 1);
                p = 1 + (t2 - m * (PP - 1));
                if (p == idx[m]) p = 0;
            }
            const float* k = cl_pos + ((size_t)(m * PP + p)) * CC;
            float2 kv = *(const float2*)(k + 2 * lane);
            float ksq = kv.x * kv.x + kv.y * kv.y;
            for (int o = 32; o; o >>= 1) ksq += __shfl_xor(ksq, o);
            float invkn = 1.0f / fmaxf(sqrtf(ksq), 1e-12f);
            if (j < NN) {
                float dt = qn[j][2 * lane] * kv.x + qn[j][2 * lane + 1] * kv.y;
                for (int o = 32; o; o >>= 1) dt += __shfl_xor(dt, o);
                float sim = fminf(fmaxf(fmaf(0.5f * invkn, dt, 0.5f), EPS), ONE_M_EPS);
                pos += -__logf(sim);
            } else {
#pragma unroll
                for (int n = 0; n < NN; n++) {
                    float dt = qn[n][2 * lane] * kv.x + qn[n][2 * lane + 1] * kv.y;
                    for (int o = 32; o; o >>= 1) dt += __shfl_xor(dt, o);
                    float om = fminf(fmaxf(fmaf(-0.5f * invkn, dt, 0.5f), EPS), ONE_M_EPS);
                    neg -= __logf(om);
                }
            }
        }
        if (!lane) { sbc[0][w] = pos; sbc[1][w] = neg; }
        __syncthreads();
        if (tid == 0) {
            ws[OFF_CLP + cb * 2 + 0] = sbc[0][0] + sbc[0][1] + sbc[0][2] + sbc[0][3];
            ws[OFF_CLP + cb * 2 + 1] = sbc[1][0] + sbc[1][1] + sbc[1][2] + sbc[1][3];
        }
    } else {
        // ---- Misc block: zero accumulators/counter, write cl_pos_save ----
        if (tid < 48) ws[OFF_ACC + tid] = 0.0f;
        if (tid == 48) *(unsigned*)(ws + OFF_DONE) = 0u;
        int n = tid >> 5, c = (tid & 31) * 4;
        int in = idx[n];
        float4 v = *(const float4*)(cl_pos + ((size_t)(n * PP + in)) * CC + c);
        *(float4*)(out + OUT_CLSAVE + n * 128 + c) = v;
    }
}

// ============ Kernel 2: combine tile partials + softmax (16 blocks) ============
// q<8: rows of batch q -> LSER + softmax(S2RAW) -> SHARP2 (ws)
// q>=8: cols of batch q-8 -> LSEC + softmax(S1RAW) -> sharp1 (out)
__global__ __launch_bounds__(256) void k2_comb(float* __restrict__ ws, float* __restrict__ out) {
    int q = blockIdx.x;
    int b = q & 7;
    bool docol = q >= 8;
    int tid = threadIdx.x;
    const float* part = ws + (docol ? OFF_CP : OFF_RP);
    int i0 = tid * 4;
    float zs[4], lse[4];
#pragma unroll
    for (int k = 0; k < 4; k++) {
        int i = i0 + k;
        float es = 0.f, mx = -1e30f, sm = 0.f, sq = 0.f;
#pragma unroll
        for (int t = 0; t < 16; t++) {
            float4 v = *(const float4*)(part + (((size_t)(b * 16 + t)) * 1024 + i) * 4);
            es += v.x; mx = fmaxf(mx, v.y); sm += v.z; sq += v.w;
        }
        lse[k] = __logf(es);
        float mean = sm * (1.0f / 1024.0f);
        float var  = (sq - sm * sm * (1.0f / 1024.0f)) * (1.0f / 1023.0f);
        zs[k] = (mx - mean) / sqrtf(fmaxf(var, 1e-30f));
    }
    *(float4*)(ws + (docol ? OFF_LSEC : OFF_LSER) + (size_t)b * 1024 + i0) =
        make_float4(lse[0], lse[1], lse[2], lse[3]);

    // block softmax over 1024 zs values
    int lane = tid & 63, wid = tid >> 6;
    __shared__ float sb[4];
    __shared__ float red;
    float mx = fmaxf(fmaxf(zs[0], zs[1]), fmaxf(zs[2], zs[3]));
    for (int o = 32; o; o >>= 1) mx = fmaxf(mx, __shfl_xor(mx, o));
    if (!lane) sb[wid] = mx;
    __syncthreads();
    if (tid == 0) red = fmaxf(fmaxf(sb[0], sb[1]), fmaxf(sb[2], sb[3]));
    __syncthreads();
    mx = red;
    float e0 = __expf(zs[0] - mx), e1 = __expf(zs[1] - mx), e2 = __expf(zs[2] - mx), e3 = __expf(zs[3] - mx);
    float sm = e0 + e1 + e2 + e3;
    for (int o = 32; o; o >>= 1) sm += __shfl_xor(sm, o);
    __syncthreads();
    if (!lane) sb[wid] = sm;
    __syncthreads();
    if (tid == 0) red = sb[0] + sb[1] + sb[2] + sb[3];
    __syncthreads();
    float inv = 1.0f / red;
    float* dst = docol ? (out + (size_t)b * 1024) : (ws + OFF_SHARP2 + (size_t)b * 1024);
    *(float4*)(dst + i0) = make_float4(e0 * inv, e1 * inv, e2 * inv, e3 * inv);
}

// ============ Kernel 3: main loss (2048 blocks) + last-block finalize ============
__device__ __forceinline__ void proc_elem(float d, int lab, float lcj, float sh1j,
                                          float lr, float s2v,
                                          float& posg, float& negg, float& l1, float& l2,
                                          float& negs, float& pcf) {
    float t = lr + lcj - d * (2.0f * INV_T);
    float isPos = (lab == 1) ? 1.0f : 0.0f;
    float isNeg = 1.0f - isPos;
    float tp   = fminf(fmaxf(t, NLL_MIN), NLL_MAX);
    float simc = fminf(fmaxf(fmaf(0.5f, d, 0.5f), EPS), ONE_M_EPS);
    float om   = fminf(fmaxf(fmaf(-0.5f, d, 0.5f), EPS), ONE_M_EPS);
    float nll2 = -__logf(simc);
    float cf   = fminf(fmaxf(__expf(-t), EPS), ONE_M_EPS);
    float nllg = -__logf(1.0f - cf);
    float nlls = -__logf(om);
    posg += isPos * tp;
    l1   += isPos * nll2 * sh1j;
    l2   += isPos * nll2 * s2v;
    pcf  += isPos;
    negg += isNeg * nllg;
    negs += isNeg * nlls;
}

__global__ __launch_bounds__(256) void k3_loss(const float* __restrict__ dot,
                                               const int* __restrict__ label,
                                               const float* __restrict__ sharp1,
                                               float* __restrict__ ws,
                                               float* __restrict__ out) {
    int b = blockIdx.y;
    int l0 = blockIdx.x * 4;
    int s = threadIdx.x * 4;
    float4 lc4 = *(const float4*)(ws + OFF_LSEC + (size_t)b * 1024 + s);
    float4 sh1 = *(const float4*)(sharp1 + (size_t)b * 1024 + s);
    const float* lser = ws + OFF_LSER + (size_t)b * 1024;
    const float* sh2  = ws + OFF_SHARP2 + (size_t)b * 1024;
    float posg = 0, negg = 0, l1 = 0, l2 = 0, negs = 0, pcf = 0;
#pragma unroll
    for (int r = 0; r < 4; r++) {
        int l = l0 + r;
        float lr  = lser[l];
        float s2v = sh2[l];
        size_t base = ((size_t)(b * 1024 + l)) * 1024 + s;
        float4 d4 = *(const float4*)(dot + base);
        int4  lb  = *(const int4*)(label + base);
        proc_elem(d4.x, lb.x, lc4.x, sh1.x, lr, s2v, posg, negg, l1, l2, negs, pcf);
        proc_elem(d4.y, lb.y, lc4.y, sh1.y, lr, s2v, posg, negg, l1, l2, negs, pcf);
        proc_elem(d4.z, lb.z, lc4.z, sh1.z, lr, s2v, posg, negg, l1, l2, negs, pcf);
        proc_elem(d4.w, lb.w, lc4.w, sh1.w, lr, s2v, posg, negg, l1, l2, negs, pcf);
    }
    float vals[6] = {posg, negg, l1, l2, negs, pcf};
    __shared__ float sb[6][4];
    int lane = threadIdx.x & 63, wid = threadIdx.x >> 6;
#pragma unroll
    for (int k = 0; k < 6; k++) {
        float v = vals[k];
        for (int o = 32; o; o >>= 1) v += __shfl_xor(v, o);
        if (!lane) sb[k][wid] = v;
    }
    __syncthreads();
    if (threadIdx.x < 6) {
        float r = sb[threadIdx.x][0] + sb[threadIdx.x][1] + sb[threadIdx.x][2] + sb[threadIdx.x][3];
        atomicAdd(ws + OFF_ACC + (size_t)b * 6 + threadIdx.x, r);
    }
    __syncthreads();
    if (threadIdx.x == 0) {
        __threadfence();
        unsigned prev = __hip_atomic_fetch_add((unsigned*)(ws + OFF_DONE), 1u,
                                               __ATOMIC_ACQ_REL, __HIP_MEMORY_SCOPE_AGENT);
        if (prev == 2048u - 1u) {
            // ---- finalize (all other blocks' atomics visible via acq on counter) ----
            float gp = 0, gn = 0, lsh = 0;
            for (int b2 = 0; b2 < 8; b2++) {
                float a[6];
#pragma unroll
                for (int k = 0; k < 6; k++)
                    a[k] = __hip_atomic_load(ws + OFF_ACC + b2 * 6 + k,
                                             __ATOMIC_RELAXED, __HIP_MEMORY_SCOPE_AGENT);
                float pc = a[5];
                float nc = (float)((size_t)LL * SS) - pc;
                gp += a[0] / fmaxf(pc, 1.0f);
                gn += a[1] / fmaxf(nc, 1.0f);
                lsh += (a[2] + a[3]) * 0.5f + a[4] / fmaxf(nc, 1.0f);
            }
            gp *= 0.125f; gn *= 0.125f; lsh *= 0.125f;
            float lgeo = gp + gn;
            float lgw = (0.5f * lgeo + 0.5f * lsh) * 0.5f;
            float clp = 0.f, cln = 0.f;
            for (int c = 0; c < 32; c++) {
                clp += ws[OFF_CLP + 2 * c + 0];
                cln += ws[OFF_CLP + 2 * c + 1];
            }
            clp /= 8.0f;
            cln /= (8.0f * 2040.0f);
            float lcl = (clp + cln) * 0.5f * 0.5f;
            out[OUT_SCAL + 0] = lgw + lcl;
            out[OUT_SCAL + 1] = gp;
            out[OUT_SCAL + 2] = gn;
            out[OUT_SCAL + 3] = lsh;
            out[OUT_SCAL + 4] = lcl;
        }
    }
}

extern "C" void kernel_launch(void* const* d_in, const int* in_sizes, int n_in,
                              void* d_out, int out_size, void* d_ws, size_t ws_size,
                              hipStream_t stream) {
    const float* q_geo   = (const float*)d_in[0];
    const float* q_cl    = (const float*)d_in[1];
    const float* geo_pos = (const float*)d_in[2];
    const float* cl_pos  = (const float*)d_in[3];
    const int*   label   = (const int*)d_in[4];
    const int*   idx     = (const int*)d_in[5];
    float* out = (float*)d_out;
    float* ws  = (float*)d_ws;
    float* dot = ws;

    k1_gemm<<<dim3(545), dim3(256), 0, stream>>>(q_geo, geo_pos, q_cl, cl_pos, idx, dot, ws, out);
    k2_comb<<<dim3(16), dim3(256), 0, stream>>>(ws, out);
    k3_loss<<<dim3(256, 8), dim3(256), 0, stream>>>(dot, label, out, ws, out);
}

// Round 8
// 165.746 us; speedup vs baseline: 1.5499x; 1.5499x over previous
//
#include <hip/hip_runtime.h>
#include <math.h>

// Problem constants
#define BB 8
#define LL 1024
#define SS 1024
#define CC 128
#define NN 8
#define PP 256

static constexpr float EPS       = 1e-6f;
static constexpr float ONE_M_EPS = 1.0f - 1e-6f;
static constexpr float INV_T     = 1.0f / 0.07f;
static constexpr float NLL_MAX   = 13.815511f;    // -log(1e-6)
static constexpr float NLL_MIN   = 1.0000005e-6f; // -log(1-1e-6)

// Workspace layout (float offsets)
static constexpr size_t DOTSZ      = (size_t)BB * LL * SS;   // 8388608
static constexpr size_t OFF_LSER   = DOTSZ;                  // B*L
static constexpr size_t OFF_S2RAW  = DOTSZ + 8192;           // B*L
static constexpr size_t OFF_LSEC   = DOTSZ + 16384;          // B*S
static constexpr size_t OFF_S1RAW  = DOTSZ + 24576;          // B*S
static constexpr size_t OFF_SHARP2 = DOTSZ + 32768;          // B*L
static constexpr size_t OFF_RP     = DOTSZ + 40960;          // row partials: 8*16*1024*4 = 524288
static constexpr size_t OFF_CP     = OFF_RP + 524288;        // col partials: 524288
static constexpr size_t OFF_ACC    = OFF_CP + 524288;        // B*6
static constexpr size_t OFF_ACCCL  = OFF_ACC + 48;           // 2
static constexpr size_t OFF_QN     = OFF_ACC + 64;           // 8*128 normalized q_sel

// Output layout (floats): sharp1[8192], cl_pos_save[1024], total, geo_pos, geo_neg, loss_sharp, loss_cl
static constexpr int OUT_CLSAVE = 8192;
static constexpr int OUT_SCAL   = 9216;

typedef __bf16 bf16x8 __attribute__((ext_vector_type(8)));
typedef float  floatx4 __attribute__((ext_vector_type(4)));

__device__ __forceinline__ bf16x8 mkfrag(unsigned a, unsigned b, unsigned c, unsigned d) {
    uint4 t = make_uint4(a, b, c, d);
    return __builtin_bit_cast(bf16x8, t);
}

// Split 4 fp32 into packed bf16 hi pairs (RNE) + lo pairs (exact residual, truncated).
__device__ __forceinline__ void split_f4(float4 x,
                                         unsigned& hp0, unsigned& hp1,
                                         unsigned& lp0, unsigned& lp1) {
    unsigned u0 = __builtin_bit_cast(unsigned, x.x);
    unsigned u1 = __builtin_bit_cast(unsigned, x.y);
    unsigned u2 = __builtin_bit_cast(unsigned, x.z);
    unsigned u3 = __builtin_bit_cast(unsigned, x.w);
    unsigned r0 = u0 + 0x7FFFu + ((u0 >> 16) & 1u);
    unsigned r1 = u1 + 0x7FFFu + ((u1 >> 16) & 1u);
    unsigned r2 = u2 + 0x7FFFu + ((u2 >> 16) & 1u);
    unsigned r3 = u3 + 0x7FFFu + ((u3 >> 16) & 1u);
    float s0 = x.x - __builtin_bit_cast(float, r0 & 0xFFFF0000u);
    float s1 = x.y - __builtin_bit_cast(float, r1 & 0xFFFF0000u);
    float s2 = x.z - __builtin_bit_cast(float, r2 & 0xFFFF0000u);
    float s3 = x.w - __builtin_bit_cast(float, r3 & 0xFFFF0000u);
    hp0 = __builtin_amdgcn_perm(r1, r0, 0x07060302u);
    hp1 = __builtin_amdgcn_perm(r3, r2, 0x07060302u);
    lp0 = __builtin_amdgcn_perm(__builtin_bit_cast(unsigned, s1),
                                __builtin_bit_cast(unsigned, s0), 0x07060302u);
    lp1 = __builtin_amdgcn_perm(__builtin_bit_cast(unsigned, s3),
                                __builtin_bit_cast(unsigned, s2), 0x07060302u);
}

// ---------------- Prep: zero accumulators, normalize q_sel, write cl_pos_save ----------------
__global__ __launch_bounds__(512) void prep(const float* __restrict__ q_cl,
                                            const float* __restrict__ cl_pos,
                                            const int* __restrict__ idx,
                                            float* __restrict__ out, float* __restrict__ ws) {
    int tid = threadIdx.x;
    if (tid < 50) ws[OFF_ACC + tid] = 0.0f;
    int n = tid >> 6, lane = tid & 63;
    int in = idx[n];
    const float* q = q_cl + ((size_t)(n * PP + in)) * CC;
    float2 qv = *(const float2*)(q + 2 * lane);
    float ss = qv.x * qv.x + qv.y * qv.y;
    for (int o = 32; o; o >>= 1) ss += __shfl_xor(ss, o);
    float inv = 1.0f / fmaxf(sqrtf(ss), 1e-12f);
    *(float2*)(ws + OFF_QN + n * 128 + 2 * lane) = make_float2(qv.x * inv, qv.y * inv);
    const float* cp = cl_pos + ((size_t)(n * PP + in)) * CC;
    float2 cv = *(const float2*)(cp + 2 * lane);
    *(float2*)(out + OUT_CLSAVE + n * 128 + 2 * lane) = cv;
}

// ---------------- GEMM: LDS-free, barrier-free. One wave per 64x64 tile (R5-verified) ----------
__global__ __launch_bounds__(256) void gemm_dot(const float* __restrict__ A,
                                                const float* __restrict__ Bm,
                                                float* __restrict__ dot,
                                                float* __restrict__ ws) {
    int tid  = threadIdx.x;
    int lane = tid & 63;
    int w    = tid >> 6;
    int t    = blockIdx.x * 4 + w;      // 0..2047
    int b    = t >> 8;
    int rem  = t & 255;
    int lt   = rem >> 4, st = rem & 15;
    int l0   = lt * 64, s0 = st * 64;
    int fl   = lane & 15;
    int quad = lane >> 4;

    const float* Ab = A  + ((size_t)b * LL + l0) * CC;
    const float* Bb = Bm + ((size_t)b * SS + s0) * CC;

    floatx4 acc[4][4];
#pragma unroll
    for (int i = 0; i < 4; i++)
#pragma unroll
        for (int j = 0; j < 4; j++) acc[i][j] = (floatx4){0.f, 0.f, 0.f, 0.f};

    for (int c0 = 0; c0 < 128; c0 += 32) {
        float4 ax[4][2], bx[4][2];
#pragma unroll
        for (int mt = 0; mt < 4; mt++) {
            const float* p = Ab + (size_t)(mt * 16 + fl) * CC + c0 + quad * 8;
            ax[mt][0] = *(const float4*)p;
            ax[mt][1] = *(const float4*)(p + 4);
        }
#pragma unroll
        for (int nt = 0; nt < 4; nt++) {
            const float* p = Bb + (size_t)(nt * 16 + fl) * CC + c0 + quad * 8;
            bx[nt][0] = *(const float4*)p;
            bx[nt][1] = *(const float4*)(p + 4);
        }
        bf16x8 ah[4], al[4];
#pragma unroll
        for (int mt = 0; mt < 4; mt++) {
            unsigned h0, h1, h2, h3, q0, q1, q2, q3;
            split_f4(ax[mt][0], h0, h1, q0, q1);
            split_f4(ax[mt][1], h2, h3, q2, q3);
            ah[mt] = mkfrag(h0, h1, h2, h3);
            al[mt] = mkfrag(q0, q1, q2, q3);
        }
#pragma unroll
        for (int nt = 0; nt < 4; nt++) {
            unsigned h0, h1, h2, h3, q0, q1, q2, q3;
            split_f4(bx[nt][0], h0, h1, q0, q1);
            split_f4(bx[nt][1], h2, h3, q2, q3);
            bf16x8 bh = mkfrag(h0, h1, h2, h3);
            bf16x8 bl = mkfrag(q0, q1, q2, q3);
#pragma unroll
            for (int mt = 0; mt < 4; mt++) {
                acc[mt][nt] = __builtin_amdgcn_mfma_f32_16x16x32_bf16(ah[mt], bh, acc[mt][nt], 0, 0, 0);
                acc[mt][nt] = __builtin_amdgcn_mfma_f32_16x16x32_bf16(ah[mt], bl, acc[mt][nt], 0, 0, 0);
                acc[mt][nt] = __builtin_amdgcn_mfma_f32_16x16x32_bf16(al[mt], bh, acc[mt][nt], 0, 0, 0);
            }
        }
    }

    // Store dot tile. C/D layout: col=lane&15, row=quad*4+reg
    float* D = dot + ((size_t)b * LL + l0) * SS + s0;
#pragma unroll
    for (int mt = 0; mt < 4; mt++)
#pragma unroll
        for (int nt = 0; nt < 4; nt++) {
            int col = nt * 16 + fl;
#pragma unroll
            for (int r = 0; r < 4; r++) {
                int row = mt * 16 + quad * 4 + r;
                D[(size_t)row * SS + col] = acc[mt][nt][r];
            }
        }

    // Fused wave-private tile statistics (no LDS, no barriers)
    float ces[4], cmx[4], csm[4], csq[4];
#pragma unroll
    for (int nt = 0; nt < 4; nt++) { ces[nt] = 0.f; cmx[nt] = -1e30f; csm[nt] = 0.f; csq[nt] = 0.f; }
#pragma unroll
    for (int mt = 0; mt < 4; mt++) {
#pragma unroll
        for (int r = 0; r < 4; r++) {
            float es = 0.f, mx = -1e30f, sm = 0.f, sq = 0.f;
#pragma unroll
            for (int nt = 0; nt < 4; nt++) {
                float d  = acc[mt][nt][r];
                float e  = __expf(d * INV_T);
                float s2 = fmaf(0.5f, d, 0.5f);
                es += e; mx = fmaxf(mx, s2); sm += s2; sq += s2 * s2;
                ces[nt] += e; cmx[nt] = fmaxf(cmx[nt], s2); csm[nt] += s2; csq[nt] += s2 * s2;
            }
            for (int o = 1; o < 16; o <<= 1) {
                es += __shfl_xor(es, o);
                mx = fmaxf(mx, __shfl_xor(mx, o));
                sm += __shfl_xor(sm, o);
                sq += __shfl_xor(sq, o);
            }
            if (fl == 0) {
                int row = l0 + mt * 16 + quad * 4 + r;
                *(float4*)(ws + OFF_RP + (((size_t)(b * 16 + st)) * 1024 + row) * 4) =
                    make_float4(es, mx, sm, sq);
            }
        }
    }
#pragma unroll
    for (int nt = 0; nt < 4; nt++) {
        float es = ces[nt], mx = cmx[nt], sm = csm[nt], sq = csq[nt];
        for (int o = 16; o < 64; o <<= 1) {
            es += __shfl_xor(es, o);
            mx = fmaxf(mx, __shfl_xor(mx, o));
            sm += __shfl_xor(sm, o);
            sq += __shfl_xor(sq, o);
        }
        if (quad == 0) {
            int col = s0 + nt * 16 + fl;
            *(float4*)(ws + OFF_CP + (((size_t)(b * 16 + lt)) * 1024 + col) * 4) =
                make_float4(es, mx, sm, sq);
        }
    }
}

// ---------------- Combine tile partials -> LSER/S2RAW (rows), LSEC/S1RAW (cols) ----------------
__global__ __launch_bounds__(256) void rc_combine(float* __restrict__ ws) {
    int g = (blockIdx.x & 31) * 256 + threadIdx.x;  // 0..8191
    bool docol = blockIdx.x >= 32;
    int b = g >> 10, i = g & 1023;
    const float* part = ws + (docol ? OFF_CP : OFF_RP);
    float es = 0.f, mx = -1e30f, sm = 0.f, sq = 0.f;
#pragma unroll
    for (int t = 0; t < 16; t++) {
        float4 v = *(const float4*)(part + (((size_t)(b * 16 + t)) * 1024 + i) * 4);
        es += v.x; mx = fmaxf(mx, v.y); sm += v.z; sq += v.w;
    }
    float mean = sm * (1.0f / 1024.0f);
    float var  = (sq - sm * sm * (1.0f / 1024.0f)) * (1.0f / 1023.0f);
    float zs   = (mx - mean) / sqrtf(fmaxf(var, 1e-30f));
    if (!docol) {
        ws[OFF_LSER + g]  = __logf(es);
        ws[OFF_S2RAW + g] = zs;
    } else {
        ws[OFF_LSEC + g]  = __logf(es);
        ws[OFF_S1RAW + g] = zs;
    }
}

// ---------------- 16 softmaxes of length 1024: 0..7 -> sharp1 (d_out), 8..15 -> sharp2 (ws) ----
__global__ __launch_bounds__(256) void softmax16(float* __restrict__ ws, float* __restrict__ out) {
    int q = blockIdx.x;
    int b = q & 7;
    const float* src = ws + ((q < 8) ? OFF_S1RAW : OFF_S2RAW) + (size_t)b * 1024;
    float* dst = (q < 8) ? (out + (size_t)b * 1024) : (ws + OFF_SHARP2 + (size_t)b * 1024);
    float4 v = ((const float4*)src)[threadIdx.x];
    int lane = threadIdx.x & 63, wid = threadIdx.x >> 6;
    __shared__ float sb[4];
    __shared__ float red;
    float mx = fmaxf(fmaxf(v.x, v.y), fmaxf(v.z, v.w));
    for (int o = 32; o; o >>= 1) mx = fmaxf(mx, __shfl_xor(mx, o));
    if (!lane) sb[wid] = mx;
    __syncthreads();
    if (threadIdx.x == 0) red = fmaxf(fmaxf(sb[0], sb[1]), fmaxf(sb[2], sb[3]));
    __syncthreads();
    mx = red;
    float e0 = __expf(v.x - mx), e1 = __expf(v.y - mx), e2 = __expf(v.z - mx), e3 = __expf(v.w - mx);
    float sm = e0 + e1 + e2 + e3;
    for (int o = 32; o; o >>= 1) sm += __shfl_xor(sm, o);
    __syncthreads();
    if (!lane) sb[wid] = sm;
    __syncthreads();
    if (threadIdx.x == 0) red = sb[0] + sb[1] + sb[2] + sb[3];
    __syncthreads();
    float inv = 1.0f / red;
    ((float4*)dst)[threadIdx.x] = make_float4(e0 * inv, e1 * inv, e2 * inv, e3 * inv);
}

// ---------------- Main elementwise loss pass: MLP-optimized ----------------
__device__ __forceinline__ void proc_elem(float d, int lab, float lcj, float sh1j,
                                          float lr, float s2v,
                                          float& posg, float& negg, float& l1, float& l2,
                                          float& negs, float& pcf) {
    float t = lr + lcj - d * (2.0f * INV_T);
    float isPos = (lab == 1) ? 1.0f : 0.0f;
    float isNeg = 1.0f - isPos;
    float tp   = fminf(fmaxf(t, NLL_MIN), NLL_MAX);
    float simc = fminf(fmaxf(fmaf(0.5f, d, 0.5f), EPS), ONE_M_EPS);
    float om   = fminf(fmaxf(fmaf(-0.5f, d, 0.5f), EPS), ONE_M_EPS);
    float nll2 = -__logf(simc);
    float cf   = fminf(fmaxf(__expf(-t), EPS), ONE_M_EPS);
    float nllg = -__logf(1.0f - cf);
    float nlls = -__logf(om);
    posg += isPos * tp;
    l1   += isPos * nll2 * sh1j;
    l2   += isPos * nll2 * s2v;
    pcf  += isPos;
    negg += isNeg * nllg;
    negs += isNeg * nlls;
}

__global__ __launch_bounds__(256, 4) void main_loss(const float* __restrict__ dot,
                                                    const int* __restrict__ label,
                                                    const float* __restrict__ sharp1,
                                                    float* __restrict__ ws) {
    int b = blockIdx.y;
    int l0 = blockIdx.x * 4;
    int s = threadIdx.x * 4;
    // headers: column stats for our 4 cols, row stats for our 4 rows (broadcast float4)
    float4 lc4  = *(const float4*)(ws + OFF_LSEC + (size_t)b * 1024 + s);
    float4 sh1  = *(const float4*)(sharp1 + (size_t)b * 1024 + s);
    float4 lr4  = *(const float4*)(ws + OFF_LSER + (size_t)b * 1024 + l0);
    float4 s2v4 = *(const float4*)(ws + OFF_SHARP2 + (size_t)b * 1024 + l0);
    // batch ALL bulk loads first: 8 outstanding global_load_dwordx4
    size_t base = ((size_t)(b * 1024 + l0)) * 1024 + s;
    float4 d4s[4];
    int4   lbs[4];
#pragma unroll
    for (int r = 0; r < 4; r++) {
        d4s[r] = *(const float4*)(dot + base + (size_t)r * 1024);
        lbs[r] = *(const int4*)(label + base + (size_t)r * 1024);
    }
    float lrs[4]  = {lr4.x, lr4.y, lr4.z, lr4.w};
    float s2vs[4] = {s2v4.x, s2v4.y, s2v4.z, s2v4.w};
    float posg = 0, negg = 0, l1 = 0, l2 = 0, negs = 0, pcf = 0;
#pragma unroll
    for (int r = 0; r < 4; r++) {
        float lr  = lrs[r];
        float s2v = s2vs[r];
        proc_elem(d4s[r].x, lbs[r].x, lc4.x, sh1.x, lr, s2v, posg, negg, l1, l2, negs, pcf);
        proc_elem(d4s[r].y, lbs[r].y, lc4.y, sh1.y, lr, s2v, posg, negg, l1, l2, negs, pcf);
        proc_elem(d4s[r].z, lbs[r].z, lc4.z, sh1.z, lr, s2v, posg, negg, l1, l2, negs, pcf);
        proc_elem(d4s[r].w, lbs[r].w, lc4.w, sh1.w, lr, s2v, posg, negg, l1, l2, negs, pcf);
    }
    float vals[6] = {posg, negg, l1, l2, negs, pcf};
    __shared__ float sb[6][4];
    int lane = threadIdx.x & 63, wid = threadIdx.x >> 6;
#pragma unroll
    for (int k = 0; k < 6; k++) {
        float v = vals[k];
        for (int o = 32; o; o >>= 1) v += __shfl_xor(v, o);
        if (!lane) sb[k][wid] = v;
    }
    __syncthreads();
    if (threadIdx.x < 6) {
        float r = sb[threadIdx.x][0] + sb[threadIdx.x][1] + sb[threadIdx.x][2] + sb[threadIdx.x][3];
        atomicAdd(ws + OFF_ACC + (size_t)b * 6 + threadIdx.x, r);
    }
}

// ---------------- Contrast loss: one wave per all_k row j ----------------
__global__ __launch_bounds__(256) void contrast(const float* __restrict__ cl_pos,
                                                const int* __restrict__ idx,
                                                float* __restrict__ ws) {
    int j = blockIdx.x * 4 + (threadIdx.x >> 6);
    int lane = threadIdx.x & 63;
    int m, p;
    if (j < NN) {
        m = j; p = idx[j];
    } else {
        int jj = j - NN;
        m = jj / (PP - 1);
        p = 1 + (jj - m * (PP - 1));
        if (p == idx[m]) p = 0;
    }
    const float* k = cl_pos + ((size_t)(m * PP + p)) * CC;
    float2 kv = *(const float2*)(k + 2 * lane);
    float ksq = kv.x * kv.x + kv.y * kv.y;
    for (int o = 32; o; o >>= 1) ksq += __shfl_xor(ksq, o);
    float invkn = 1.0f / fmaxf(sqrtf(ksq), 1e-12f);
    float pos = 0.0f, neg = 0.0f;
    if (j < NN) {
        const float2 qv = *(const float2*)(ws + OFF_QN + j * 128 + 2 * lane);
        float dt = qv.x * kv.x + qv.y * kv.y;
        for (int o = 32; o; o >>= 1) dt += __shfl_xor(dt, o);
        float sim = fminf(fmaxf(fmaf(0.5f * invkn, dt, 0.5f), EPS), ONE_M_EPS);
        pos = -__logf(sim);
    } else {
#pragma unroll
        for (int n = 0; n < NN; n++) {
            const float2 qv = *(const float2*)(ws + OFF_QN + n * 128 + 2 * lane);
            float dt = qv.x * kv.x + qv.y * kv.y;
            for (int o = 32; o; o >>= 1) dt += __shfl_xor(dt, o);
            float om = fminf(fmaxf(fmaf(-0.5f * invkn, dt, 0.5f), EPS), ONE_M_EPS);
            neg -= __logf(om);
        }
    }
    __shared__ float sb[2][4];
    int w = threadIdx.x >> 6;
    if (!lane) { sb[0][w] = pos; sb[1][w] = neg; }
    __syncthreads();
    if (threadIdx.x == 0) {
        float ps = sb[0][0] + sb[0][1] + sb[0][2] + sb[0][3];
        float ng = sb[1][0] + sb[1][1] + sb[1][2] + sb[1][3];
        if (ps != 0.0f) atomicAdd(ws + OFF_ACCCL + 0, ps);
        if (ng != 0.0f) atomicAdd(ws + OFF_ACCCL + 1, ng);
    }
}

// ---------------- Final scalar combine ----------------
__global__ void finalize(float* __restrict__ out, const float* __restrict__ ws) {
    if (threadIdx.x != 0) return;
    float gp = 0, gn = 0, lsh = 0;
    for (int b = 0; b < 8; b++) {
        const float* a = ws + OFF_ACC + (size_t)b * 6;
        float pc = a[5];
        float nc = (float)((size_t)LL * SS) - pc;
        gp += a[0] / fmaxf(pc, 1.0f);
        gn += a[1] / fmaxf(nc, 1.0f);
        lsh += (a[2] + a[3]) * 0.5f + a[4] / fmaxf(nc, 1.0f);
    }
    gp *= 0.125f; gn *= 0.125f; lsh *= 0.125f;
    float lgeo = gp + gn;
    float lgw = (0.5f * lgeo + 0.5f * lsh) * 0.5f;
    float clp = ws[OFF_ACCCL + 0] / 8.0f;
    float cln = ws[OFF_ACCCL + 1] / (8.0f * 2040.0f);
    float lcl = (clp + cln) * 0.5f * 0.5f;
    out[OUT_SCAL + 0] = lgw + lcl;
    out[OUT_SCAL + 1] = gp;
    out[OUT_SCAL + 2] = gn;
    out[OUT_SCAL + 3] = lsh;
    out[OUT_SCAL + 4] = lcl;
}

extern "C" void kernel_launch(void* const* d_in, const int* in_sizes, int n_in,
                              void* d_out, int out_size, void* d_ws, size_t ws_size,
                              hipStream_t stream) {
    const float* q_geo   = (const float*)d_in[0];
    const float* q_cl    = (const float*)d_in[1];
    const float* geo_pos = (const float*)d_in[2];
    const float* cl_pos  = (const float*)d_in[3];
    const int*   label   = (const int*)d_in[4];
    const int*   idx     = (const int*)d_in[5];
    float* out = (float*)d_out;
    float* ws  = (float*)d_ws;
    float* dot = ws;

    prep<<<dim3(1), dim3(512), 0, stream>>>(q_cl, cl_pos, idx, out, ws);
    gemm_dot<<<dim3(512), dim3(256), 0, stream>>>(q_geo, geo_pos, dot, ws);
    rc_combine<<<dim3(64), dim3(256), 0, stream>>>(ws);
    softmax16<<<dim3(16), dim3(256), 0, stream>>>(ws, out);
    main_loss<<<dim3(256, 8), dim3(256), 0, stream>>>(dot, label, out, ws);
    contrast<<<dim3(512), dim3(256), 0, stream>>>(cl_pos, idx, ws);
    finalize<<<dim3(1), dim3(64), 0, stream>>>(out, ws);
}